// Round 2
// baseline (3837.332 us; speedup 1.0000x reference)
//
#include <hip/hip_runtime.h>
#include <math.h>

#define NN 50000
#define EE 600000
#define IND 128
#define HIDD 64
#define NH 4
#define EDD 16
#define OUTD 2
#define C1 256  /* NH*HIDD */

__device__ __forceinline__ float lrelu(float v){ return v > 0.f ? v : 0.2f*v; }
__device__ __forceinline__ unsigned fkey(float f){
    unsigned u = __float_as_uint(f);
    return (u & 0x80000000u) ? ~u : (u | 0x80000000u);
}
__device__ __forceinline__ float fdec(unsigned k){
    unsigned u = (k & 0x80000000u) ? (k & 0x7FFFFFFFu) : ~k;
    return __uint_as_float(u);
}

// ---------------- layer 1 node linear: xl1 = x@W1l+b1l, xr1 = x@W1r+b1r ----
__global__ __launch_bounds__(256) void k_lin1(
    const float* __restrict__ x, const float* __restrict__ Wl, const float* __restrict__ bl,
    const float* __restrict__ Wr, const float* __restrict__ br,
    float* __restrict__ xl, float* __restrict__ xr)
{
    __shared__ float As[16 * IND];
    int t = threadIdx.x;
    int row0 = blockIdx.x * 16;
#pragma unroll
    for (int j = 0; j < 8; ++j) {
        int idx = t + j * 256;
        int r = idx >> 7, c = idx & 127;
        As[idx] = (row0 + r < NN) ? x[(size_t)(row0 + r) * IND + c] : 0.f;
    }
    __syncthreads();
    float accl[16], accr[16];
    float bL = bl[t], bR = br[t];
#pragma unroll
    for (int i = 0; i < 16; ++i) { accl[i] = bL; accr[i] = bR; }
    for (int k = 0; k < IND; k += 4) {
        float wl0 = Wl[(k+0) * C1 + t], wl1 = Wl[(k+1) * C1 + t];
        float wl2 = Wl[(k+2) * C1 + t], wl3 = Wl[(k+3) * C1 + t];
        float wr0 = Wr[(k+0) * C1 + t], wr1 = Wr[(k+1) * C1 + t];
        float wr2 = Wr[(k+2) * C1 + t], wr3 = Wr[(k+3) * C1 + t];
#pragma unroll
        for (int i = 0; i < 16; ++i) {
            float4 a = *((const float4*)&As[i * IND + k]);
            accl[i] = fmaf(a.x, wl0, accl[i]); accl[i] = fmaf(a.y, wl1, accl[i]);
            accl[i] = fmaf(a.z, wl2, accl[i]); accl[i] = fmaf(a.w, wl3, accl[i]);
            accr[i] = fmaf(a.x, wr0, accr[i]); accr[i] = fmaf(a.y, wr1, accr[i]);
            accr[i] = fmaf(a.z, wr2, accr[i]); accr[i] = fmaf(a.w, wr3, accr[i]);
        }
    }
#pragma unroll
    for (int i = 0; i < 16; ++i) {
        int r = row0 + i;
        if (r < NN) {
            xl[(size_t)r * C1 + t] = accl[i];
            xr[(size_t)r * C1 + t] = accr[i];
        }
    }
}

// ---------------- layer 1 edge logits + segment max -------------------------
// lane owns channels 4*lane .. 4*lane+3 (head = lane>>4); We cached in VGPRs
__global__ __launch_bounds__(256) void k_elog1(
    const int* __restrict__ src, const int* __restrict__ dst,
    const float* __restrict__ ea, const float* __restrict__ We, const float* __restrict__ be,
    const float* __restrict__ att, const float* __restrict__ xl, const float* __restrict__ xr,
    float* __restrict__ logits, unsigned* __restrict__ amax)
{
    int t = threadIdx.x, lane = t & 63, w = t >> 6;
    int c4 = lane * 4;
    int h = lane >> 4;
    float4 Wreg[16];
#pragma unroll
    for (int k = 0; k < 16; ++k) Wreg[k] = *((const float4*)(We + k * C1 + c4));
    float4 sb4 = *((const float4*)(be + c4));
    float4 sa4 = *((const float4*)(att + c4));
    for (int e = blockIdx.x * 4 + w; e < EE; e += gridDim.x * 4) {
        int s = src[e], d = dst[e];
        float4 xl4 = *((const float4*)(xl + (size_t)s * C1 + c4));
        float4 xr4 = *((const float4*)(xr + (size_t)d * C1 + c4));
        float4 ea4[4];
#pragma unroll
        for (int j = 0; j < 4; ++j) ea4[j] = *((const float4*)(ea + (size_t)e * EDD + j * 4));
        float4 xe = sb4;
#pragma unroll
        for (int j = 0; j < 4; ++j) {
            float ev[4] = {ea4[j].x, ea4[j].y, ea4[j].z, ea4[j].w};
#pragma unroll
            for (int q = 0; q < 4; ++q) {
                float4 wv = Wreg[j * 4 + q];
                xe.x = fmaf(ev[q], wv.x, xe.x);
                xe.y = fmaf(ev[q], wv.y, xe.y);
                xe.z = fmaf(ev[q], wv.z, xe.z);
                xe.w = fmaf(ev[q], wv.w, xe.w);
            }
        }
        float mx = lrelu(xl4.x + xr4.x + xe.x);
        float my = lrelu(xl4.y + xr4.y + xe.y);
        float mz = lrelu(xl4.z + xr4.z + xe.z);
        float mw = lrelu(xl4.w + xr4.w + xe.w);
        float p = mx * sa4.x + my * sa4.y + mz * sa4.z + mw * sa4.w;
        p += __shfl_down(p, 8, 64);
        p += __shfl_down(p, 4, 64);
        p += __shfl_down(p, 2, 64);
        p += __shfl_down(p, 1, 64);
        if ((lane & 15) == 0) {
            logits[(size_t)e * NH + h] = p;
            atomicMax(&amax[d * NH + h], fkey(p));
        }
    }
}

// ---------------- layer 1 exp + segment sum ---------------------------------
__global__ void k_exp1(const int* __restrict__ dst, float* __restrict__ logits,
                       const unsigned* __restrict__ amax, float* __restrict__ denom)
{
    int stride = gridDim.x * blockDim.x;
    for (int i = blockIdx.x * blockDim.x + threadIdx.x; i < EE * NH; i += stride) {
        int e = i >> 2, h = i & 3;
        int d = dst[e];
        float mx = fdec(amax[d * NH + h]);
        float ex = __expf(logits[i] - mx);
        logits[i] = ex;
        atomicAdd(&denom[d * NH + h], ex);
    }
}

// ---------------- layer 1 aggregation (atomic scatter, float4 gathers) ------
__global__ __launch_bounds__(256) void k_agg1(
    const int* __restrict__ src, const int* __restrict__ dst,
    const float* __restrict__ exv, const float* __restrict__ denom,
    const float* __restrict__ xl, float* __restrict__ h1)
{
    int t = threadIdx.x, lane = t & 63, w = t >> 6;
    int c4 = lane * 4;
    int h = lane >> 4;
    for (int e = blockIdx.x * 4 + w; e < EE; e += gridDim.x * 4) {
        int s = src[e], d = dst[e];
        float al = exv[(size_t)e * NH + h] / denom[d * NH + h];
        float4 xv = *((const float4*)(xl + (size_t)s * C1 + c4));
        float* hp = h1 + (size_t)d * C1 + c4;
        atomicAdd(hp + 0, al * xv.x);
        atomicAdd(hp + 1, al * xv.y);
        atomicAdd(hp + 2, al * xv.z);
        atomicAdd(hp + 3, al * xv.w);
    }
}

// ---------------- layer 2 node linear (fuses bias1+relu on load) ------------
__global__ __launch_bounds__(256) void k_lin2(
    const float* __restrict__ h1acc, const float* __restrict__ bias1,
    const float* __restrict__ Wl, const float* __restrict__ bl,
    const float* __restrict__ Wr, const float* __restrict__ br,
    float* __restrict__ xl2, float* __restrict__ xr2)
{
    __shared__ float As[16 * 260];  // pad 260 (mult of 4 -> aligned float4 rows)
    int t = threadIdx.x;
    int row0 = blockIdx.x * 16;
    float b1 = bias1[t];
#pragma unroll
    for (int j = 0; j < 16; ++j) {
        float v = (row0 + j < NN) ? h1acc[(size_t)(row0 + j) * C1 + t] : 0.f;
        v = v + b1;
        As[j * 260 + t] = v > 0.f ? v : 0.f;
    }
    __syncthreads();
    int col = t & 63, g = t >> 6;
    float accl[4], accr[4];
    float bL = bl[col], bR = br[col];
#pragma unroll
    for (int i = 0; i < 4; ++i) { accl[i] = bL; accr[i] = bR; }
    for (int k = 0; k < C1; k += 4) {
        float wl0 = Wl[(k+0) * HIDD + col], wl1 = Wl[(k+1) * HIDD + col];
        float wl2 = Wl[(k+2) * HIDD + col], wl3 = Wl[(k+3) * HIDD + col];
        float wr0 = Wr[(k+0) * HIDD + col], wr1 = Wr[(k+1) * HIDD + col];
        float wr2 = Wr[(k+2) * HIDD + col], wr3 = Wr[(k+3) * HIDD + col];
#pragma unroll
        for (int i = 0; i < 4; ++i) {
            float4 a = *((const float4*)&As[(g * 4 + i) * 260 + k]);
            accl[i] = fmaf(a.x, wl0, accl[i]); accl[i] = fmaf(a.y, wl1, accl[i]);
            accl[i] = fmaf(a.z, wl2, accl[i]); accl[i] = fmaf(a.w, wl3, accl[i]);
            accr[i] = fmaf(a.x, wr0, accr[i]); accr[i] = fmaf(a.y, wr1, accr[i]);
            accr[i] = fmaf(a.z, wr2, accr[i]); accr[i] = fmaf(a.w, wr3, accr[i]);
        }
    }
#pragma unroll
    for (int i = 0; i < 4; ++i) {
        int r = row0 + g * 4 + i;
        if (r < NN) {
            xl2[(size_t)r * HIDD + col] = accl[i];
            xr2[(size_t)r * HIDD + col] = accr[i];
        }
    }
}

// ---------------- layer 2 edge logits: 4 edges per wave ---------------------
__global__ __launch_bounds__(256) void k_elog2(
    const int* __restrict__ src, const int* __restrict__ dst,
    const float* __restrict__ ea, const float* __restrict__ We, const float* __restrict__ be,
    const float* __restrict__ att, const float* __restrict__ xl, const float* __restrict__ xr,
    float* __restrict__ logits, unsigned* __restrict__ amax)
{
    int t = threadIdx.x, lane = t & 63, w = t >> 6;
    int sub = lane & 15, grp = lane >> 4;
    int c4 = sub * 4;
    float4 Wreg[16];
#pragma unroll
    for (int k = 0; k < 16; ++k) Wreg[k] = *((const float4*)(We + k * HIDD + c4));
    float4 sb4 = *((const float4*)(be + c4));
    float4 sa4 = *((const float4*)(att + c4));
    for (int eb = blockIdx.x * 16 + w * 4; eb < EE; eb += gridDim.x * 16) {
        int e = eb + grp;
        int s = src[e], d = dst[e];
        float4 xl4 = *((const float4*)(xl + (size_t)s * HIDD + c4));
        float4 xr4 = *((const float4*)(xr + (size_t)d * HIDD + c4));
        float4 ea4[4];
#pragma unroll
        for (int j = 0; j < 4; ++j) ea4[j] = *((const float4*)(ea + (size_t)e * EDD + j * 4));
        float4 xe = sb4;
#pragma unroll
        for (int j = 0; j < 4; ++j) {
            float ev[4] = {ea4[j].x, ea4[j].y, ea4[j].z, ea4[j].w};
#pragma unroll
            for (int q = 0; q < 4; ++q) {
                float4 wv = Wreg[j * 4 + q];
                xe.x = fmaf(ev[q], wv.x, xe.x);
                xe.y = fmaf(ev[q], wv.y, xe.y);
                xe.z = fmaf(ev[q], wv.z, xe.z);
                xe.w = fmaf(ev[q], wv.w, xe.w);
            }
        }
        float mx = lrelu(xl4.x + xr4.x + xe.x);
        float my = lrelu(xl4.y + xr4.y + xe.y);
        float mz = lrelu(xl4.z + xr4.z + xe.z);
        float mw = lrelu(xl4.w + xr4.w + xe.w);
        float p = mx * sa4.x + my * sa4.y + mz * sa4.z + mw * sa4.w;
        p += __shfl_down(p, 8, 64);
        p += __shfl_down(p, 4, 64);
        p += __shfl_down(p, 2, 64);
        p += __shfl_down(p, 1, 64);
        if (sub == 0) { logits[e] = p; atomicMax(&amax[d], fkey(p)); }
    }
}

// ---------------- layer 2 exp + segment sum ---------------------------------
__global__ void k_exp2(const int* __restrict__ dst, float* __restrict__ logits,
                       const unsigned* __restrict__ amax, float* __restrict__ denom)
{
    int stride = gridDim.x * blockDim.x;
    for (int e = blockIdx.x * blockDim.x + threadIdx.x; e < EE; e += stride) {
        int d = dst[e];
        float ex = __expf(logits[e] - fdec(amax[d]));
        logits[e] = ex;
        atomicAdd(&denom[d], ex);
    }
}

// ---------------- layer 2 aggregation: 4 edges per wave ---------------------
__global__ __launch_bounds__(256) void k_agg2(
    const int* __restrict__ src, const int* __restrict__ dst,
    const float* __restrict__ exv, const float* __restrict__ denom,
    const float* __restrict__ xl2, float* __restrict__ h2)
{
    int t = threadIdx.x, lane = t & 63, w = t >> 6;
    int sub = lane & 15, grp = lane >> 4;
    int c4 = sub * 4;
    for (int eb = blockIdx.x * 16 + w * 4; eb < EE; eb += gridDim.x * 16) {
        int e = eb + grp;
        int s = src[e], d = dst[e];
        float al = exv[e] / denom[d];
        float4 xv = *((const float4*)(xl2 + (size_t)s * HIDD + c4));
        float* hp = h2 + (size_t)d * HIDD + c4;
        atomicAdd(hp + 0, al * xv.x);
        atomicAdd(hp + 1, al * xv.y);
        atomicAdd(hp + 2, al * xv.z);
        atomicAdd(hp + 3, al * xv.w);
    }
}

// ---------------- finalize h2 = relu(h2 + bias2) ----------------------------
__global__ void k_fin2(float* __restrict__ h2, const float* __restrict__ bias2)
{
    int stride = gridDim.x * blockDim.x;
    int nv = NN * HIDD / 4;
    const float4* b4 = (const float4*)bias2;
    float4* h4 = (float4*)h2;
    for (int i = blockIdx.x * blockDim.x + threadIdx.x; i < nv; i += stride) {
        float4 v = h4[i];
        float4 b = b4[i & 15];
        v.x += b.x; v.y += b.y; v.z += b.z; v.w += b.w;
        v.x = v.x > 0.f ? v.x : 0.f;
        v.y = v.y > 0.f ? v.y : 0.f;
        v.z = v.z > 0.f ? v.z : 0.f;
        v.w = v.w > 0.f ? v.w : 0.f;
        h4[i] = v;
    }
}

// ---------------- edge MLP: 32-edge tile, LDS-tiled GEMM --------------------
#define TE 32
__global__ __launch_bounds__(256) void k_mlp(
    const int* __restrict__ src, const int* __restrict__ dst,
    const float* __restrict__ h2, const float* __restrict__ ea,
    const float* __restrict__ Wm1, const float* __restrict__ bm1,
    const float* __restrict__ Wm2, const float* __restrict__ bm2,
    float* __restrict__ out)
{
    __shared__ float sW1t[64][148];   // [c][k] transposed; pad 148 -> 2-way aliasing (free)
    __shared__ float sEf[TE][148];    // [edge][k]
    __shared__ float sW2[128];
    __shared__ float sb1[64];
    int t = threadIdx.x, lane = t & 63, w = t >> 6;
    for (int idx = t; idx < 144 * 64; idx += 256) {
        int k = idx >> 6, c = idx & 63;
        sW1t[c][k] = Wm1[idx];
    }
    if (t < 128) sW2[t] = Wm2[t];
    if (t < 64)  sb1[t] = bm1[t];
    __syncthreads();
    float b20 = bm2[0], b21 = bm2[1];
    float w20 = sW2[lane * 2], w21 = sW2[lane * 2 + 1];
    float bini = sb1[lane];
    for (int base = blockIdx.x * TE; base < EE; base += gridDim.x * TE) {
        // stage 32 edges' features; wave w stages edges w*8..w*8+7
#pragma unroll
        for (int j = 0; j < 8; ++j) {
            int le = w * 8 + j;
            int e = base + le;
            if (e < EE) {
                if (lane < 16) {
                    int s = src[e];
                    float4 v = ((const float4*)(h2 + (size_t)s * HIDD))[lane];
                    ((float4*)&sEf[le][0])[lane] = v;
                } else if (lane < 32) {
                    int d = dst[e];
                    float4 v = ((const float4*)(h2 + (size_t)d * HIDD))[lane - 16];
                    ((float4*)&sEf[le][64])[lane - 16] = v;
                } else if (lane < 36) {
                    float4 v = ((const float4*)(ea + (size_t)e * EDD))[lane - 32];
                    ((float4*)&sEf[le][128])[lane - 32] = v;
                }
            }
        }
        __syncthreads();
        // compute: wave w handles edges w*8..w*8+7; lane = hidden channel
        float acc[8];
#pragma unroll
        for (int i = 0; i < 8; ++i) acc[i] = bini;
        for (int k = 0; k < 144; k += 4) {
            float4 wv = *((const float4*)&sW1t[lane][k]);
#pragma unroll
            for (int i = 0; i < 8; ++i) {
                float4 ef = *((const float4*)&sEf[w * 8 + i][k]);
                acc[i] = fmaf(ef.x, wv.x, acc[i]);
                acc[i] = fmaf(ef.y, wv.y, acc[i]);
                acc[i] = fmaf(ef.z, wv.z, acc[i]);
                acc[i] = fmaf(ef.w, wv.w, acc[i]);
            }
        }
#pragma unroll
        for (int i = 0; i < 8; ++i) {
            float hl = acc[i] > 0.f ? acc[i] : 0.f;
            float o0 = hl * w20, o1 = hl * w21;
#pragma unroll
            for (int off = 32; off > 0; off >>= 1) {
                o0 += __shfl_down(o0, off, 64);
                o1 += __shfl_down(o1, off, 64);
            }
            int e = base + w * 8 + i;
            if (lane == 0 && e < EE) {
                ((float2*)out)[e] = make_float2(o0 + b20, o1 + b21);
            }
        }
        __syncthreads();
    }
}

extern "C" void kernel_launch(void* const* d_in, const int* in_sizes, int n_in,
                              void* d_out, int out_size, void* d_ws, size_t ws_size,
                              hipStream_t stream)
{
    const float* x    = (const float*)d_in[0];
    const int*   ei   = (const int*)d_in[1];
    const float* ea   = (const float*)d_in[2];
    const float* W1l  = (const float*)d_in[3];
    const float* b1l  = (const float*)d_in[4];
    const float* W1r  = (const float*)d_in[5];
    const float* b1r  = (const float*)d_in[6];
    const float* W1e  = (const float*)d_in[7];
    const float* b1e  = (const float*)d_in[8];
    const float* att1 = (const float*)d_in[9];
    const float* bias1= (const float*)d_in[10];
    const float* W2l  = (const float*)d_in[11];
    const float* b2l  = (const float*)d_in[12];
    const float* W2r  = (const float*)d_in[13];
    const float* b2r  = (const float*)d_in[14];
    const float* W2e  = (const float*)d_in[15];
    const float* b2e  = (const float*)d_in[16];
    const float* att2 = (const float*)d_in[17];
    const float* bias2= (const float*)d_in[18];
    const float* Wm1  = (const float*)d_in[19];
    const float* bm1  = (const float*)d_in[20];
    const float* Wm2  = (const float*)d_in[21];
    const float* bm2  = (const float*)d_in[22];
    float* out = (float*)d_out;
    const int* srcp = ei;
    const int* dstp = ei + EE;

    float* ws = (float*)d_ws;
    size_t o_xl1    = 0;
    size_t o_xr1    = o_xl1 + (size_t)NN * C1;
    size_t o_h1     = o_xr1 + (size_t)NN * C1;       // ---- zeroed region starts here
    size_t o_amax1  = o_h1 + (size_t)NN * C1;
    size_t o_denom1 = o_amax1 + (size_t)NN * NH;
    size_t o_h2     = o_denom1 + (size_t)NN * NH;
    size_t o_amax2  = o_h2 + (size_t)NN * HIDD;
    size_t o_denom2 = o_amax2 + (size_t)NN;
    size_t o_zend   = o_denom2 + (size_t)NN;         // ---- zeroed region ends here
    size_t o_logits1= o_zend;
    size_t o_logits2= o_logits1 + (size_t)EE * NH;
    size_t o_xl2    = o_logits2 + (size_t)EE;
    size_t o_xr2    = o_xl2 + (size_t)NN * HIDD;

    hipMemsetAsync(ws + o_h1, 0, (o_zend - o_h1) * sizeof(float), stream);

    dim3 blk(256);
    k_lin1<<<(NN + 15) / 16, blk, 0, stream>>>(x, W1l, b1l, W1r, b1r, ws + o_xl1, ws + o_xr1);
    k_elog1<<<4096, blk, 0, stream>>>(srcp, dstp, ea, W1e, b1e, att1,
                                      ws + o_xl1, ws + o_xr1,
                                      ws + o_logits1, (unsigned*)(ws + o_amax1));
    k_exp1<<<2048, blk, 0, stream>>>(dstp, ws + o_logits1,
                                     (const unsigned*)(ws + o_amax1), ws + o_denom1);
    k_agg1<<<4096, blk, 0, stream>>>(srcp, dstp, ws + o_logits1, ws + o_denom1,
                                     ws + o_xl1, ws + o_h1);
    k_lin2<<<(NN + 15) / 16, blk, 0, stream>>>(ws + o_h1, bias1, W2l, b2l, W2r, b2r,
                                               ws + o_xl2, ws + o_xr2);
    k_elog2<<<4096, blk, 0, stream>>>(srcp, dstp, ea, W2e, b2e, att2,
                                      ws + o_xl2, ws + o_xr2,
                                      ws + o_logits2, (unsigned*)(ws + o_amax2));
    k_exp2<<<2048, blk, 0, stream>>>(dstp, ws + o_logits2,
                                     (const unsigned*)(ws + o_amax2), ws + o_denom2);
    k_agg2<<<4096, blk, 0, stream>>>(srcp, dstp, ws + o_logits2, ws + o_denom2,
                                     ws + o_xl2, ws + o_h2);
    k_fin2<<<1024, blk, 0, stream>>>(ws + o_h2, bias2);
    k_mlp<<<4096, blk, 0, stream>>>(srcp, dstp, ws + o_h2, ea, Wm1, bm1, Wm2, bm2, out);
}

// Round 3
// 1457.795 us; speedup vs baseline: 2.6323x; 2.6323x over previous
//
#include <hip/hip_runtime.h>
#include <math.h>

#define NN 50000
#define EE 600000
#define IND 128
#define HIDD 64
#define NH 4
#define EDD 16
#define OUTD 2
#define C1 256  /* NH*HIDD */

__device__ __forceinline__ float lrelu(float v){ return v > 0.f ? v : 0.2f*v; }

// ---------------- CSR build: histogram ---------------------------------------
__global__ __launch_bounds__(256) void k_hist(const int* __restrict__ dst, int* __restrict__ cnt)
{
    int stride = gridDim.x * blockDim.x;
    for (int e = blockIdx.x * blockDim.x + threadIdx.x; e < EE; e += stride)
        atomicAdd(&cnt[dst[e]], 1);
}

// ---------------- CSR build: exclusive scan (single block, 1024 thr) ---------
__global__ __launch_bounds__(1024) void k_scan(const int* __restrict__ cnt, int* __restrict__ rs)
{
    __shared__ int wsum[16];
    __shared__ int wpref[16];
    int t = threadIdx.x, lane = t & 63, w = t >> 6;
    int running = 0;
    for (int base = 0; base < NN; base += 1024) {
        int idx = base + t;
        int v = (idx < NN) ? cnt[idx] : 0;
        int sc = v;
#pragma unroll
        for (int off = 1; off < 64; off <<= 1) {
            int u = __shfl_up(sc, off, 64);
            if (lane >= off) sc += u;
        }
        if (lane == 63) wsum[w] = sc;
        __syncthreads();
        if (w == 0 && lane < 16) {
            int x = wsum[lane];
#pragma unroll
            for (int off = 1; off < 16; off <<= 1) {
                int u = __shfl_up(x, off, 64);
                if (lane >= off) x += u;
            }
            wpref[lane] = x;
        }
        __syncthreads();
        int woff = (w == 0) ? 0 : wpref[w - 1];
        if (idx < NN) rs[idx] = running + woff + sc - v;
        running += wpref[15];
        __syncthreads();
    }
    if (t == 0) rs[NN] = running;
}

// ---------------- CSR build: scatter edge ids --------------------------------
__global__ __launch_bounds__(256) void k_scatter(
    const int* __restrict__ src, const int* __restrict__ dst,
    const int* __restrict__ rs, int* __restrict__ cur,
    int* __restrict__ eid, int* __restrict__ esrc)
{
    int stride = gridDim.x * blockDim.x;
    for (int e = blockIdx.x * blockDim.x + threadIdx.x; e < EE; e += stride) {
        int d = dst[e];
        int p = rs[d] + atomicAdd(&cur[d], 1);
        eid[p] = e;
        esrc[p] = src[e];
    }
}

// ---------------- layer 1 node linear: xl1 = x@W1l+b1l, xr1 = x@W1r+b1r ------
__global__ __launch_bounds__(256) void k_lin1(
    const float* __restrict__ x, const float* __restrict__ Wl, const float* __restrict__ bl,
    const float* __restrict__ Wr, const float* __restrict__ br,
    float* __restrict__ xl, float* __restrict__ xr)
{
    __shared__ float As[16 * IND];
    int t = threadIdx.x;
    int row0 = blockIdx.x * 16;
#pragma unroll
    for (int j = 0; j < 8; ++j) {
        int idx = t + j * 256;
        int r = idx >> 7, c = idx & 127;
        As[idx] = (row0 + r < NN) ? x[(size_t)(row0 + r) * IND + c] : 0.f;
    }
    __syncthreads();
    float accl[16], accr[16];
    float bL = bl[t], bR = br[t];
#pragma unroll
    for (int i = 0; i < 16; ++i) { accl[i] = bL; accr[i] = bR; }
    for (int k = 0; k < IND; k += 4) {
        float wl0 = Wl[(k+0) * C1 + t], wl1 = Wl[(k+1) * C1 + t];
        float wl2 = Wl[(k+2) * C1 + t], wl3 = Wl[(k+3) * C1 + t];
        float wr0 = Wr[(k+0) * C1 + t], wr1 = Wr[(k+1) * C1 + t];
        float wr2 = Wr[(k+2) * C1 + t], wr3 = Wr[(k+3) * C1 + t];
#pragma unroll
        for (int i = 0; i < 16; ++i) {
            float4 a = *((const float4*)&As[i * IND + k]);
            accl[i] = fmaf(a.x, wl0, accl[i]); accl[i] = fmaf(a.y, wl1, accl[i]);
            accl[i] = fmaf(a.z, wl2, accl[i]); accl[i] = fmaf(a.w, wl3, accl[i]);
            accr[i] = fmaf(a.x, wr0, accr[i]); accr[i] = fmaf(a.y, wr1, accr[i]);
            accr[i] = fmaf(a.z, wr2, accr[i]); accr[i] = fmaf(a.w, wr3, accr[i]);
        }
    }
#pragma unroll
    for (int i = 0; i < 16; ++i) {
        int r = row0 + i;
        if (r < NN) {
            xl[(size_t)r * C1 + t] = accl[i];
            xr[(size_t)r * C1 + t] = accr[i];
        }
    }
}

// ---------------- layer 1 fused GAT: wave per node, online softmax -----------
__global__ __launch_bounds__(256) void k_gat1(
    const int* __restrict__ rs, const int* __restrict__ eid, const int* __restrict__ esrc,
    const float* __restrict__ ea, const float* __restrict__ We, const float* __restrict__ be,
    const float* __restrict__ att, const float* __restrict__ xl, const float* __restrict__ xr,
    float* __restrict__ h1)
{
    int t = threadIdx.x, lane = t & 63, w = t >> 6;
    int c4 = lane * 4;                 // lane owns 4 contiguous channels, head = lane>>4
    float4 Wreg[16];
#pragma unroll
    for (int k = 0; k < 16; ++k) Wreg[k] = *((const float4*)(We + k * C1 + c4));
    float4 sb4 = *((const float4*)(be + c4));
    float4 sa4 = *((const float4*)(att + c4));
    for (int n = blockIdx.x * 4 + w; n < NN; n += gridDim.x * 4) {
        int beg = rs[n], end = rs[n + 1];
        float4 xr4 = *((const float4*)(xr + (size_t)n * C1 + c4));
        float m = -INFINITY, den = 0.f;
        float4 acc = make_float4(0.f, 0.f, 0.f, 0.f);
        for (int i = beg; i < end; ++i) {
            int e = eid[i], s = esrc[i];
            float4 xl4 = *((const float4*)(xl + (size_t)s * C1 + c4));
            float4 ea0 = *((const float4*)(ea + (size_t)e * EDD));
            float4 ea1 = *((const float4*)(ea + (size_t)e * EDD + 4));
            float4 ea2 = *((const float4*)(ea + (size_t)e * EDD + 8));
            float4 ea3 = *((const float4*)(ea + (size_t)e * EDD + 12));
            float ev[16] = {ea0.x, ea0.y, ea0.z, ea0.w, ea1.x, ea1.y, ea1.z, ea1.w,
                            ea2.x, ea2.y, ea2.z, ea2.w, ea3.x, ea3.y, ea3.z, ea3.w};
            float4 xe = sb4;
#pragma unroll
            for (int k = 0; k < 16; ++k) {
                xe.x = fmaf(ev[k], Wreg[k].x, xe.x);
                xe.y = fmaf(ev[k], Wreg[k].y, xe.y);
                xe.z = fmaf(ev[k], Wreg[k].z, xe.z);
                xe.w = fmaf(ev[k], Wreg[k].w, xe.w);
            }
            float vx = lrelu(xl4.x + xr4.x + xe.x);
            float vy = lrelu(xl4.y + xr4.y + xe.y);
            float vz = lrelu(xl4.z + xr4.z + xe.z);
            float vw = lrelu(xl4.w + xr4.w + xe.w);
            float p = vx * sa4.x + vy * sa4.y + vz * sa4.z + vw * sa4.w;
            // butterfly sum within 16-lane head group -> all lanes get head logit
            p += __shfl_xor(p, 1, 64);
            p += __shfl_xor(p, 2, 64);
            p += __shfl_xor(p, 4, 64);
            p += __shfl_xor(p, 8, 64);
            float mn = fmaxf(m, p);
            float scl = __expf(m - mn);
            float el  = __expf(p - mn);
            den = fmaf(den, scl, el);
            acc.x = fmaf(acc.x, scl, el * xl4.x);
            acc.y = fmaf(acc.y, scl, el * xl4.y);
            acc.z = fmaf(acc.z, scl, el * xl4.z);
            acc.w = fmaf(acc.w, scl, el * xl4.w);
            m = mn;
        }
        float r = den > 0.f ? 1.f / den : 0.f;
        float4 o = make_float4(acc.x * r, acc.y * r, acc.z * r, acc.w * r);
        *((float4*)(h1 + (size_t)n * C1 + c4)) = o;
    }
}

// ---------------- layer 2 node linear (fuses bias1+relu on load) -------------
__global__ __launch_bounds__(256) void k_lin2(
    const float* __restrict__ h1acc, const float* __restrict__ bias1,
    const float* __restrict__ Wl, const float* __restrict__ bl,
    const float* __restrict__ Wr, const float* __restrict__ br,
    float* __restrict__ xl2, float* __restrict__ xr2)
{
    __shared__ float As[16 * 260];
    int t = threadIdx.x;
    int row0 = blockIdx.x * 16;
    float b1 = bias1[t];
#pragma unroll
    for (int j = 0; j < 16; ++j) {
        float v = (row0 + j < NN) ? h1acc[(size_t)(row0 + j) * C1 + t] : 0.f;
        v = v + b1;
        As[j * 260 + t] = v > 0.f ? v : 0.f;
    }
    __syncthreads();
    int col = t & 63, g = t >> 6;
    float accl[4], accr[4];
    float bL = bl[col], bR = br[col];
#pragma unroll
    for (int i = 0; i < 4; ++i) { accl[i] = bL; accr[i] = bR; }
    for (int k = 0; k < C1; k += 4) {
        float wl0 = Wl[(k+0) * HIDD + col], wl1 = Wl[(k+1) * HIDD + col];
        float wl2 = Wl[(k+2) * HIDD + col], wl3 = Wl[(k+3) * HIDD + col];
        float wr0 = Wr[(k+0) * HIDD + col], wr1 = Wr[(k+1) * HIDD + col];
        float wr2 = Wr[(k+2) * HIDD + col], wr3 = Wr[(k+3) * HIDD + col];
#pragma unroll
        for (int i = 0; i < 4; ++i) {
            float4 a = *((const float4*)&As[(g * 4 + i) * 260 + k]);
            accl[i] = fmaf(a.x, wl0, accl[i]); accl[i] = fmaf(a.y, wl1, accl[i]);
            accl[i] = fmaf(a.z, wl2, accl[i]); accl[i] = fmaf(a.w, wl3, accl[i]);
            accr[i] = fmaf(a.x, wr0, accr[i]); accr[i] = fmaf(a.y, wr1, accr[i]);
            accr[i] = fmaf(a.z, wr2, accr[i]); accr[i] = fmaf(a.w, wr3, accr[i]);
        }
    }
#pragma unroll
    for (int i = 0; i < 4; ++i) {
        int r = row0 + g * 4 + i;
        if (r < NN) {
            xl2[(size_t)r * HIDD + col] = accl[i];
            xr2[(size_t)r * HIDD + col] = accr[i];
        }
    }
}

// ---------------- layer 2 fused GAT: wave per node, fuses bias2+relu ---------
__global__ __launch_bounds__(256) void k_gat2(
    const int* __restrict__ rs, const int* __restrict__ eid, const int* __restrict__ esrc,
    const float* __restrict__ ea, const float* __restrict__ We, const float* __restrict__ be,
    const float* __restrict__ att, const float* __restrict__ xl, const float* __restrict__ xr,
    const float* __restrict__ bias2, float* __restrict__ h2)
{
    int t = threadIdx.x, lane = t & 63, w = t >> 6;
    float Wreg[16];
#pragma unroll
    for (int k = 0; k < 16; ++k) Wreg[k] = We[k * HIDD + lane];
    float bev = be[lane], sav = att[lane], b2 = bias2[lane];
    for (int n = blockIdx.x * 4 + w; n < NN; n += gridDim.x * 4) {
        int beg = rs[n], end = rs[n + 1];
        float xrv = xr[(size_t)n * HIDD + lane];
        float m = -INFINITY, den = 0.f, acc = 0.f;
        for (int i = beg; i < end; ++i) {
            int e = eid[i], s = esrc[i];
            float xlv = xl[(size_t)s * HIDD + lane];
            float4 ea0 = *((const float4*)(ea + (size_t)e * EDD));
            float4 ea1 = *((const float4*)(ea + (size_t)e * EDD + 4));
            float4 ea2 = *((const float4*)(ea + (size_t)e * EDD + 8));
            float4 ea3 = *((const float4*)(ea + (size_t)e * EDD + 12));
            float ev[16] = {ea0.x, ea0.y, ea0.z, ea0.w, ea1.x, ea1.y, ea1.z, ea1.w,
                            ea2.x, ea2.y, ea2.z, ea2.w, ea3.x, ea3.y, ea3.z, ea3.w};
            float xe = bev;
#pragma unroll
            for (int k = 0; k < 16; ++k) xe = fmaf(ev[k], Wreg[k], xe);
            float v = lrelu(xlv + xrv + xe);
            float p = v * sav;
            p += __shfl_xor(p, 1, 64);
            p += __shfl_xor(p, 2, 64);
            p += __shfl_xor(p, 4, 64);
            p += __shfl_xor(p, 8, 64);
            p += __shfl_xor(p, 16, 64);
            p += __shfl_xor(p, 32, 64);
            float mn = fmaxf(m, p);
            float scl = __expf(m - mn);
            float el  = __expf(p - mn);
            den = fmaf(den, scl, el);
            acc = fmaf(acc, scl, el * xlv);
            m = mn;
        }
        float r = den > 0.f ? 1.f / den : 0.f;
        float o = fmaf(acc, r, b2);
        h2[(size_t)n * HIDD + lane] = o > 0.f ? o : 0.f;
    }
}

// ---------------- edge MLP: 32-edge tile, LDS-tiled GEMM ---------------------
#define TE 32
__global__ __launch_bounds__(256) void k_mlp(
    const int* __restrict__ src, const int* __restrict__ dst,
    const float* __restrict__ h2, const float* __restrict__ ea,
    const float* __restrict__ Wm1, const float* __restrict__ bm1,
    const float* __restrict__ Wm2, const float* __restrict__ bm2,
    float* __restrict__ out)
{
    __shared__ float sW1t[64][148];
    __shared__ float sEf[TE][148];
    __shared__ float sW2[128];
    __shared__ float sb1[64];
    int t = threadIdx.x, lane = t & 63, w = t >> 6;
    for (int idx = t; idx < 144 * 64; idx += 256) {
        int k = idx >> 6, c = idx & 63;
        sW1t[c][k] = Wm1[idx];
    }
    if (t < 128) sW2[t] = Wm2[t];
    if (t < 64)  sb1[t] = bm1[t];
    __syncthreads();
    float b20 = bm2[0], b21 = bm2[1];
    float w20 = sW2[lane * 2], w21 = sW2[lane * 2 + 1];
    float bini = sb1[lane];
    for (int base = blockIdx.x * TE; base < EE; base += gridDim.x * TE) {
#pragma unroll
        for (int j = 0; j < 8; ++j) {
            int le = w * 8 + j;
            int e = base + le;
            if (e < EE) {
                if (lane < 16) {
                    int s = src[e];
                    float4 v = ((const float4*)(h2 + (size_t)s * HIDD))[lane];
                    ((float4*)&sEf[le][0])[lane] = v;
                } else if (lane < 32) {
                    int d = dst[e];
                    float4 v = ((const float4*)(h2 + (size_t)d * HIDD))[lane - 16];
                    ((float4*)&sEf[le][64])[lane - 16] = v;
                } else if (lane < 36) {
                    float4 v = ((const float4*)(ea + (size_t)e * EDD))[lane - 32];
                    ((float4*)&sEf[le][128])[lane - 32] = v;
                }
            }
        }
        __syncthreads();
        float acc[8];
#pragma unroll
        for (int i = 0; i < 8; ++i) acc[i] = bini;
        for (int k = 0; k < 144; k += 4) {
            float4 wv = *((const float4*)&sW1t[lane][k]);
#pragma unroll
            for (int i = 0; i < 8; ++i) {
                float4 ef = *((const float4*)&sEf[w * 8 + i][k]);
                acc[i] = fmaf(ef.x, wv.x, acc[i]);
                acc[i] = fmaf(ef.y, wv.y, acc[i]);
                acc[i] = fmaf(ef.z, wv.z, acc[i]);
                acc[i] = fmaf(ef.w, wv.w, acc[i]);
            }
        }
#pragma unroll
        for (int i = 0; i < 8; ++i) {
            float hl = acc[i] > 0.f ? acc[i] : 0.f;
            float o0 = hl * w20, o1 = hl * w21;
#pragma unroll
            for (int off = 32; off > 0; off >>= 1) {
                o0 += __shfl_down(o0, off, 64);
                o1 += __shfl_down(o1, off, 64);
            }
            int e = base + w * 8 + i;
            if (lane == 0 && e < EE) {
                ((float2*)out)[e] = make_float2(o0 + b20, o1 + b21);
            }
        }
        __syncthreads();
    }
}

extern "C" void kernel_launch(void* const* d_in, const int* in_sizes, int n_in,
                              void* d_out, int out_size, void* d_ws, size_t ws_size,
                              hipStream_t stream)
{
    const float* x    = (const float*)d_in[0];
    const int*   ei   = (const int*)d_in[1];
    const float* ea   = (const float*)d_in[2];
    const float* W1l  = (const float*)d_in[3];
    const float* b1l  = (const float*)d_in[4];
    const float* W1r  = (const float*)d_in[5];
    const float* b1r  = (const float*)d_in[6];
    const float* W1e  = (const float*)d_in[7];
    const float* b1e  = (const float*)d_in[8];
    const float* att1 = (const float*)d_in[9];
    const float* bias1= (const float*)d_in[10];
    const float* W2l  = (const float*)d_in[11];
    const float* b2l  = (const float*)d_in[12];
    const float* W2r  = (const float*)d_in[13];
    const float* b2r  = (const float*)d_in[14];
    const float* W2e  = (const float*)d_in[15];
    const float* b2e  = (const float*)d_in[16];
    const float* att2 = (const float*)d_in[17];
    const float* bias2= (const float*)d_in[18];
    const float* Wm1  = (const float*)d_in[19];
    const float* bm1  = (const float*)d_in[20];
    const float* Wm2  = (const float*)d_in[21];
    const float* bm2  = (const float*)d_in[22];
    float* out = (float*)d_out;
    const int* srcp = ei;
    const int* dstp = ei + EE;

    float* ws = (float*)d_ws;
    const size_t NC1 = (size_t)NN * C1;      // 12.8M
    const size_t NH64 = (size_t)NN * HIDD;   // 3.2M
    size_t o_xl1 = 0;
    size_t o_xr1 = o_xl1 + NC1;
    size_t o_h1  = o_xr1 + NC1;
    size_t o_xl2 = o_h1 + NC1;
    size_t o_xr2 = o_xl2 + NH64;
    size_t o_h2  = o_xr2 + NH64;
    size_t o_cnt = o_h2 + NH64;              // int region starts here
    size_t o_rs  = o_cnt + 2 * (size_t)NN;   // cnt + cursor (zeroed together)
    size_t o_eid = o_rs + (size_t)NN + 8;
    size_t o_esrc= o_eid + (size_t)EE;

    int* cnt  = (int*)(ws + o_cnt);
    int* cur  = cnt + NN;
    int* rs   = (int*)(ws + o_rs);
    int* eid  = (int*)(ws + o_eid);
    int* esrc = (int*)(ws + o_esrc);

    hipMemsetAsync(cnt, 0, 2 * (size_t)NN * sizeof(int), stream);

    dim3 blk(256);
    k_hist<<<1024, blk, 0, stream>>>(dstp, cnt);
    k_scan<<<1, 1024, 0, stream>>>(cnt, rs);
    k_scatter<<<1024, blk, 0, stream>>>(srcp, dstp, rs, cur, eid, esrc);

    k_lin1<<<(NN + 15) / 16, blk, 0, stream>>>(x, W1l, b1l, W1r, b1r, ws + o_xl1, ws + o_xr1);
    k_gat1<<<12500, blk, 0, stream>>>(rs, eid, esrc, ea, W1e, b1e, att1,
                                      ws + o_xl1, ws + o_xr1, ws + o_h1);
    k_lin2<<<(NN + 15) / 16, blk, 0, stream>>>(ws + o_h1, bias1, W2l, b2l, W2r, b2r,
                                               ws + o_xl2, ws + o_xr2);
    k_gat2<<<12500, blk, 0, stream>>>(rs, eid, esrc, ea, W2e, b2e, att2,
                                      ws + o_xl2, ws + o_xr2, bias2, ws + o_h2);
    k_mlp<<<4096, blk, 0, stream>>>(srcp, dstp, ws + o_h2, ea, Wm1, bm1, Wm2, bm2, out);
}

// Round 4
// 1328.878 us; speedup vs baseline: 2.8876x; 1.0970x over previous
//
#include <hip/hip_runtime.h>
#include <math.h>

#define NN 50000
#define EE 600000
#define IND 128
#define HIDD 64
#define NH 4
#define EDD 16
#define OUTD 2
#define C1 256  /* NH*HIDD */

__device__ __forceinline__ float lrelu(float v){ return v > 0.f ? v : 0.2f*v; }

// ---------------- CSR build: histogram ---------------------------------------
__global__ __launch_bounds__(256) void k_hist(const int* __restrict__ dst, int* __restrict__ cnt)
{
    int stride = gridDim.x * blockDim.x;
    for (int e = blockIdx.x * blockDim.x + threadIdx.x; e < EE; e += stride)
        atomicAdd(&cnt[dst[e]], 1);
}

// ---------------- CSR build: exclusive scan (single block, 1024 thr) ---------
__global__ __launch_bounds__(1024) void k_scan(const int* __restrict__ cnt, int* __restrict__ rs)
{
    __shared__ int wsum[16];
    __shared__ int wpref[16];
    int t = threadIdx.x, lane = t & 63, w = t >> 6;
    int running = 0;
    for (int base = 0; base < NN; base += 1024) {
        int idx = base + t;
        int v = (idx < NN) ? cnt[idx] : 0;
        int sc = v;
#pragma unroll
        for (int off = 1; off < 64; off <<= 1) {
            int u = __shfl_up(sc, off, 64);
            if (lane >= off) sc += u;
        }
        if (lane == 63) wsum[w] = sc;
        __syncthreads();
        if (w == 0 && lane < 16) {
            int x = wsum[lane];
#pragma unroll
            for (int off = 1; off < 16; off <<= 1) {
                int u = __shfl_up(x, off, 64);
                if (lane >= off) x += u;
            }
            wpref[lane] = x;
        }
        __syncthreads();
        int woff = (w == 0) ? 0 : wpref[w - 1];
        if (idx < NN) rs[idx] = running + woff + sc - v;
        running += wpref[15];
        __syncthreads();
    }
    if (t == 0) rs[NN] = running;
}

// ---------------- CSR build: scatter edge ids --------------------------------
__global__ __launch_bounds__(256) void k_scatter(
    const int* __restrict__ src, const int* __restrict__ dst,
    const int* __restrict__ rs, int* __restrict__ cur,
    int* __restrict__ eid, int* __restrict__ esrc)
{
    int stride = gridDim.x * blockDim.x;
    for (int e = blockIdx.x * blockDim.x + threadIdx.x; e < EE; e += stride) {
        int d = dst[e];
        int p = rs[d] + atomicAdd(&cur[d], 1);
        eid[p] = e;
        esrc[p] = src[e];
    }
}

// ---------------- layer 1 node linear: xl1 = x@W1l+b1l, xr1 = x@W1r+b1r ------
__global__ __launch_bounds__(256) void k_lin1(
    const float* __restrict__ x, const float* __restrict__ Wl, const float* __restrict__ bl,
    const float* __restrict__ Wr, const float* __restrict__ br,
    float* __restrict__ xl, float* __restrict__ xr)
{
    __shared__ float As[16 * IND];
    int t = threadIdx.x;
    int row0 = blockIdx.x * 16;
#pragma unroll
    for (int j = 0; j < 8; ++j) {
        int idx = t + j * 256;
        int r = idx >> 7, c = idx & 127;
        As[idx] = (row0 + r < NN) ? x[(size_t)(row0 + r) * IND + c] : 0.f;
    }
    __syncthreads();
    float accl[16], accr[16];
    float bL = bl[t], bR = br[t];
#pragma unroll
    for (int i = 0; i < 16; ++i) { accl[i] = bL; accr[i] = bR; }
    for (int k = 0; k < IND; k += 4) {
        float wl0 = Wl[(k+0) * C1 + t], wl1 = Wl[(k+1) * C1 + t];
        float wl2 = Wl[(k+2) * C1 + t], wl3 = Wl[(k+3) * C1 + t];
        float wr0 = Wr[(k+0) * C1 + t], wr1 = Wr[(k+1) * C1 + t];
        float wr2 = Wr[(k+2) * C1 + t], wr3 = Wr[(k+3) * C1 + t];
#pragma unroll
        for (int i = 0; i < 16; ++i) {
            float4 a = *((const float4*)&As[i * IND + k]);
            accl[i] = fmaf(a.x, wl0, accl[i]); accl[i] = fmaf(a.y, wl1, accl[i]);
            accl[i] = fmaf(a.z, wl2, accl[i]); accl[i] = fmaf(a.w, wl3, accl[i]);
            accr[i] = fmaf(a.x, wr0, accr[i]); accr[i] = fmaf(a.y, wr1, accr[i]);
            accr[i] = fmaf(a.z, wr2, accr[i]); accr[i] = fmaf(a.w, wr3, accr[i]);
        }
    }
#pragma unroll
    for (int i = 0; i < 16; ++i) {
        int r = row0 + i;
        if (r < NN) {
            xl[(size_t)r * C1 + t] = accl[i];
            xr[(size_t)r * C1 + t] = accr[i];
        }
    }
}

// ---------------- layer 1 fused GAT: wave per node, online softmax -----------
__global__ __launch_bounds__(256) void k_gat1(
    const int* __restrict__ rs, const int* __restrict__ eid, const int* __restrict__ esrc,
    const float* __restrict__ ea, const float* __restrict__ We, const float* __restrict__ be,
    const float* __restrict__ att, const float* __restrict__ xl, const float* __restrict__ xr,
    float* __restrict__ h1)
{
    int t = threadIdx.x, lane = t & 63, w = t >> 6;
    int c4 = lane * 4;                 // lane owns 4 contiguous channels, head = lane>>4
    float4 Wreg[16];
#pragma unroll
    for (int k = 0; k < 16; ++k) Wreg[k] = *((const float4*)(We + k * C1 + c4));
    float4 sb4 = *((const float4*)(be + c4));
    float4 sa4 = *((const float4*)(att + c4));
    for (int n = blockIdx.x * 4 + w; n < NN; n += gridDim.x * 4) {
        int beg = rs[n], end = rs[n + 1];
        float4 xr4 = *((const float4*)(xr + (size_t)n * C1 + c4));
        float m = -INFINITY, den = 0.f;
        float4 acc = make_float4(0.f, 0.f, 0.f, 0.f);
        for (int i = beg; i < end; ++i) {
            int e = eid[i], s = esrc[i];
            float4 xl4 = *((const float4*)(xl + (size_t)s * C1 + c4));
            float4 ea0 = *((const float4*)(ea + (size_t)e * EDD));
            float4 ea1 = *((const float4*)(ea + (size_t)e * EDD + 4));
            float4 ea2 = *((const float4*)(ea + (size_t)e * EDD + 8));
            float4 ea3 = *((const float4*)(ea + (size_t)e * EDD + 12));
            float ev[16] = {ea0.x, ea0.y, ea0.z, ea0.w, ea1.x, ea1.y, ea1.z, ea1.w,
                            ea2.x, ea2.y, ea2.z, ea2.w, ea3.x, ea3.y, ea3.z, ea3.w};
            float4 xe = sb4;
#pragma unroll
            for (int k = 0; k < 16; ++k) {
                xe.x = fmaf(ev[k], Wreg[k].x, xe.x);
                xe.y = fmaf(ev[k], Wreg[k].y, xe.y);
                xe.z = fmaf(ev[k], Wreg[k].z, xe.z);
                xe.w = fmaf(ev[k], Wreg[k].w, xe.w);
            }
            float vx = lrelu(xl4.x + xr4.x + xe.x);
            float vy = lrelu(xl4.y + xr4.y + xe.y);
            float vz = lrelu(xl4.z + xr4.z + xe.z);
            float vw = lrelu(xl4.w + xr4.w + xe.w);
            float p = vx * sa4.x + vy * sa4.y + vz * sa4.z + vw * sa4.w;
            // butterfly sum within 16-lane head group -> all lanes get head logit
            p += __shfl_xor(p, 1, 64);
            p += __shfl_xor(p, 2, 64);
            p += __shfl_xor(p, 4, 64);
            p += __shfl_xor(p, 8, 64);
            float mn = fmaxf(m, p);
            float scl = __expf(m - mn);
            float el  = __expf(p - mn);
            den = fmaf(den, scl, el);
            acc.x = fmaf(acc.x, scl, el * xl4.x);
            acc.y = fmaf(acc.y, scl, el * xl4.y);
            acc.z = fmaf(acc.z, scl, el * xl4.z);
            acc.w = fmaf(acc.w, scl, el * xl4.w);
            m = mn;
        }
        float r = den > 0.f ? 1.f / den : 0.f;
        float4 o = make_float4(acc.x * r, acc.y * r, acc.z * r, acc.w * r);
        *((float4*)(h1 + (size_t)n * C1 + c4)) = o;
    }
}

// ---------------- layer 2 node linear (fuses bias1+relu on load) -------------
__global__ __launch_bounds__(256) void k_lin2(
    const float* __restrict__ h1acc, const float* __restrict__ bias1,
    const float* __restrict__ Wl, const float* __restrict__ bl,
    const float* __restrict__ Wr, const float* __restrict__ br,
    float* __restrict__ xl2, float* __restrict__ xr2)
{
    __shared__ float As[16 * 260];
    int t = threadIdx.x;
    int row0 = blockIdx.x * 16;
    float b1 = bias1[t];
#pragma unroll
    for (int j = 0; j < 16; ++j) {
        float v = (row0 + j < NN) ? h1acc[(size_t)(row0 + j) * C1 + t] : 0.f;
        v = v + b1;
        As[j * 260 + t] = v > 0.f ? v : 0.f;
    }
    __syncthreads();
    int col = t & 63, g = t >> 6;
    float accl[4], accr[4];
    float bL = bl[col], bR = br[col];
#pragma unroll
    for (int i = 0; i < 4; ++i) { accl[i] = bL; accr[i] = bR; }
    for (int k = 0; k < C1; k += 4) {
        float wl0 = Wl[(k+0) * HIDD + col], wl1 = Wl[(k+1) * HIDD + col];
        float wl2 = Wl[(k+2) * HIDD + col], wl3 = Wl[(k+3) * HIDD + col];
        float wr0 = Wr[(k+0) * HIDD + col], wr1 = Wr[(k+1) * HIDD + col];
        float wr2 = Wr[(k+2) * HIDD + col], wr3 = Wr[(k+3) * HIDD + col];
#pragma unroll
        for (int i = 0; i < 4; ++i) {
            float4 a = *((const float4*)&As[(g * 4 + i) * 260 + k]);
            accl[i] = fmaf(a.x, wl0, accl[i]); accl[i] = fmaf(a.y, wl1, accl[i]);
            accl[i] = fmaf(a.z, wl2, accl[i]); accl[i] = fmaf(a.w, wl3, accl[i]);
            accr[i] = fmaf(a.x, wr0, accr[i]); accr[i] = fmaf(a.y, wr1, accr[i]);
            accr[i] = fmaf(a.z, wr2, accr[i]); accr[i] = fmaf(a.w, wr3, accr[i]);
        }
    }
#pragma unroll
    for (int i = 0; i < 4; ++i) {
        int r = row0 + g * 4 + i;
        if (r < NN) {
            xl2[(size_t)r * HIDD + col] = accl[i];
            xr2[(size_t)r * HIDD + col] = accr[i];
        }
    }
}

// ---------------- layer 2 fused GAT: wave per node, fuses bias2+relu ---------
__global__ __launch_bounds__(256) void k_gat2(
    const int* __restrict__ rs, const int* __restrict__ eid, const int* __restrict__ esrc,
    const float* __restrict__ ea, const float* __restrict__ We, const float* __restrict__ be,
    const float* __restrict__ att, const float* __restrict__ xl, const float* __restrict__ xr,
    const float* __restrict__ bias2, float* __restrict__ h2)
{
    int t = threadIdx.x, lane = t & 63, w = t >> 6;
    float Wreg[16];
#pragma unroll
    for (int k = 0; k < 16; ++k) Wreg[k] = We[k * HIDD + lane];
    float bev = be[lane], sav = att[lane], b2 = bias2[lane];
    for (int n = blockIdx.x * 4 + w; n < NN; n += gridDim.x * 4) {
        int beg = rs[n], end = rs[n + 1];
        float xrv = xr[(size_t)n * HIDD + lane];
        float m = -INFINITY, den = 0.f, acc = 0.f;
        for (int i = beg; i < end; ++i) {
            int e = eid[i], s = esrc[i];
            float xlv = xl[(size_t)s * HIDD + lane];
            float4 ea0 = *((const float4*)(ea + (size_t)e * EDD));
            float4 ea1 = *((const float4*)(ea + (size_t)e * EDD + 4));
            float4 ea2 = *((const float4*)(ea + (size_t)e * EDD + 8));
            float4 ea3 = *((const float4*)(ea + (size_t)e * EDD + 12));
            float ev[16] = {ea0.x, ea0.y, ea0.z, ea0.w, ea1.x, ea1.y, ea1.z, ea1.w,
                            ea2.x, ea2.y, ea2.z, ea2.w, ea3.x, ea3.y, ea3.z, ea3.w};
            float xe = bev;
#pragma unroll
            for (int k = 0; k < 16; ++k) xe = fmaf(ev[k], Wreg[k], xe);
            float v = lrelu(xlv + xrv + xe);
            float p = v * sav;
            p += __shfl_xor(p, 1, 64);
            p += __shfl_xor(p, 2, 64);
            p += __shfl_xor(p, 4, 64);
            p += __shfl_xor(p, 8, 64);
            p += __shfl_xor(p, 16, 64);
            p += __shfl_xor(p, 32, 64);
            float mn = fmaxf(m, p);
            float scl = __expf(m - mn);
            float el  = __expf(p - mn);
            den = fmaf(den, scl, el);
            acc = fmaf(acc, scl, el * xlv);
            m = mn;
        }
        float r = den > 0.f ? 1.f / den : 0.f;
        float o = fmaf(acc, r, b2);
        h2[(size_t)n * HIDD + lane] = o > 0.f ? o : 0.f;
    }
}

// ---------------- edge MLP: register-tiled GEMM [600k x 144] @ [144 x 64] ----
// Block: 64-edge x 64-channel tile. Thread: 4 edges x 4 channels, k-chunk 4.
// Per wave per k-chunk: 8 LDS b128 (mostly broadcast) per 128 FMA-cycles.
#define APITCH 148
__global__ __launch_bounds__(256) void k_mlp(
    const int* __restrict__ src, const int* __restrict__ dst,
    const float* __restrict__ h2, const float* __restrict__ ea,
    const float* __restrict__ Wm1, const float* __restrict__ bm1,
    const float* __restrict__ Wm2, const float* __restrict__ bm2,
    float* __restrict__ out)
{
    __shared__ float As[64 * APITCH];   // 37.9 KB, [edge][k]
    __shared__ float Bs[144 * 64];      // 36.9 KB, [k][c] (native Wm1 layout)
    int t = threadIdx.x, lane = t & 63, w = t >> 6;
    // stage B once per block
    for (int idx = t; idx < 144 * 64 / 4; idx += 256)
        ((float4*)Bs)[idx] = ((const float4*)Wm1)[idx];

    int tx = t & 15, ty = t >> 4;       // tx: channel grp, ty: edge grp
    int c4 = tx * 4, e4 = ty * 4;
    float4 binit = *((const float4*)(bm1 + c4));
    float w2c00 = Wm2[(c4+0)*2], w2c01 = Wm2[(c4+0)*2+1];
    float w2c10 = Wm2[(c4+1)*2], w2c11 = Wm2[(c4+1)*2+1];
    float w2c20 = Wm2[(c4+2)*2], w2c21 = Wm2[(c4+2)*2+1];
    float w2c30 = Wm2[(c4+3)*2], w2c31 = Wm2[(c4+3)*2+1];
    float b20 = bm2[0], b21 = bm2[1];

    // EE = 9375 * 64 exactly -> every tile is full, no bounds checks
    for (int base = blockIdx.x * 64; base < EE; base += gridDim.x * 64) {
        // stage A: wave w stages edges w*16 .. w*16+15
#pragma unroll
        for (int j = 0; j < 16; ++j) {
            int le = w * 16 + j;
            int e = base + le;
            if (lane < 16) {
                int s = src[e];
                float4 v = ((const float4*)(h2 + (size_t)s * HIDD))[lane];
                ((float4*)&As[le * APITCH])[lane] = v;
            } else if (lane < 32) {
                int d = dst[e];
                float4 v = ((const float4*)(h2 + (size_t)d * HIDD))[lane - 16];
                ((float4*)&As[le * APITCH + 64])[lane - 16] = v;
            } else if (lane < 36) {
                float4 v = ((const float4*)(ea + (size_t)e * EDD))[lane - 32];
                ((float4*)&As[le * APITCH + 128])[lane - 32] = v;
            }
        }
        __syncthreads();
        float4 acc[4];
#pragma unroll
        for (int i = 0; i < 4; ++i) acc[i] = binit;
        const float* A0 = &As[(e4 + 0) * APITCH];
        const float* A1 = &As[(e4 + 1) * APITCH];
        const float* A2 = &As[(e4 + 2) * APITCH];
        const float* A3 = &As[(e4 + 3) * APITCH];
        for (int k = 0; k < 144; k += 4) {
            float4 b0 = *((const float4*)&Bs[(k+0) * 64 + c4]);
            float4 b1 = *((const float4*)&Bs[(k+1) * 64 + c4]);
            float4 b2 = *((const float4*)&Bs[(k+2) * 64 + c4]);
            float4 b3 = *((const float4*)&Bs[(k+3) * 64 + c4]);
            float4 av[4];
            av[0] = *((const float4*)(A0 + k));
            av[1] = *((const float4*)(A1 + k));
            av[2] = *((const float4*)(A2 + k));
            av[3] = *((const float4*)(A3 + k));
#pragma unroll
            for (int i = 0; i < 4; ++i) {
                acc[i].x = fmaf(av[i].x, b0.x, acc[i].x);
                acc[i].y = fmaf(av[i].x, b0.y, acc[i].y);
                acc[i].z = fmaf(av[i].x, b0.z, acc[i].z);
                acc[i].w = fmaf(av[i].x, b0.w, acc[i].w);
                acc[i].x = fmaf(av[i].y, b1.x, acc[i].x);
                acc[i].y = fmaf(av[i].y, b1.y, acc[i].y);
                acc[i].z = fmaf(av[i].y, b1.z, acc[i].z);
                acc[i].w = fmaf(av[i].y, b1.w, acc[i].w);
                acc[i].x = fmaf(av[i].z, b2.x, acc[i].x);
                acc[i].y = fmaf(av[i].z, b2.y, acc[i].y);
                acc[i].z = fmaf(av[i].z, b2.z, acc[i].z);
                acc[i].w = fmaf(av[i].z, b2.w, acc[i].w);
                acc[i].x = fmaf(av[i].w, b3.x, acc[i].x);
                acc[i].y = fmaf(av[i].w, b3.y, acc[i].y);
                acc[i].z = fmaf(av[i].w, b3.z, acc[i].z);
                acc[i].w = fmaf(av[i].w, b3.w, acc[i].w);
            }
        }
        // epilogue: relu -> W2 (64x2) -> reduce across the 16 tx lanes
#pragma unroll
        for (int i = 0; i < 4; ++i) {
            float hx = fmaxf(acc[i].x, 0.f);
            float hy = fmaxf(acc[i].y, 0.f);
            float hz = fmaxf(acc[i].z, 0.f);
            float hw = fmaxf(acc[i].w, 0.f);
            float p0 = hx * w2c00 + hy * w2c10 + hz * w2c20 + hw * w2c30;
            float p1 = hx * w2c01 + hy * w2c11 + hz * w2c21 + hw * w2c31;
            p0 += __shfl_xor(p0, 1, 64);
            p0 += __shfl_xor(p0, 2, 64);
            p0 += __shfl_xor(p0, 4, 64);
            p0 += __shfl_xor(p0, 8, 64);
            p1 += __shfl_xor(p1, 1, 64);
            p1 += __shfl_xor(p1, 2, 64);
            p1 += __shfl_xor(p1, 4, 64);
            p1 += __shfl_xor(p1, 8, 64);
            if (tx == 0) ((float2*)out)[base + e4 + i] = make_float2(p0 + b20, p1 + b21);
        }
        __syncthreads();
    }
}

extern "C" void kernel_launch(void* const* d_in, const int* in_sizes, int n_in,
                              void* d_out, int out_size, void* d_ws, size_t ws_size,
                              hipStream_t stream)
{
    const float* x    = (const float*)d_in[0];
    const int*   ei   = (const int*)d_in[1];
    const float* ea   = (const float*)d_in[2];
    const float* W1l  = (const float*)d_in[3];
    const float* b1l  = (const float*)d_in[4];
    const float* W1r  = (const float*)d_in[5];
    const float* b1r  = (const float*)d_in[6];
    const float* W1e  = (const float*)d_in[7];
    const float* b1e  = (const float*)d_in[8];
    const float* att1 = (const float*)d_in[9];
    const float* bias1= (const float*)d_in[10];
    const float* W2l  = (const float*)d_in[11];
    const float* b2l  = (const float*)d_in[12];
    const float* W2r  = (const float*)d_in[13];
    const float* b2r  = (const float*)d_in[14];
    const float* W2e  = (const float*)d_in[15];
    const float* b2e  = (const float*)d_in[16];
    const float* att2 = (const float*)d_in[17];
    const float* bias2= (const float*)d_in[18];
    const float* Wm1  = (const float*)d_in[19];
    const float* bm1  = (const float*)d_in[20];
    const float* Wm2  = (const float*)d_in[21];
    const float* bm2  = (const float*)d_in[22];
    float* out = (float*)d_out;
    const int* srcp = ei;
    const int* dstp = ei + EE;

    float* ws = (float*)d_ws;
    const size_t NC1 = (size_t)NN * C1;      // 12.8M
    const size_t NH64 = (size_t)NN * HIDD;   // 3.2M
    size_t o_xl1 = 0;
    size_t o_xr1 = o_xl1 + NC1;
    size_t o_h1  = o_xr1 + NC1;
    size_t o_xl2 = o_h1 + NC1;
    size_t o_xr2 = o_xl2 + NH64;
    size_t o_h2  = o_xr2 + NH64;
    size_t o_cnt = o_h2 + NH64;              // int region starts here
    size_t o_rs  = o_cnt + 2 * (size_t)NN;   // cnt + cursor (zeroed together)
    size_t o_eid = o_rs + (size_t)NN + 8;
    size_t o_esrc= o_eid + (size_t)EE;

    int* cnt  = (int*)(ws + o_cnt);
    int* cur  = cnt + NN;
    int* rs   = (int*)(ws + o_rs);
    int* eid  = (int*)(ws + o_eid);
    int* esrc = (int*)(ws + o_esrc);

    hipMemsetAsync(cnt, 0, 2 * (size_t)NN * sizeof(int), stream);

    dim3 blk(256);
    k_hist<<<1024, blk, 0, stream>>>(dstp, cnt);
    k_scan<<<1, 1024, 0, stream>>>(cnt, rs);
    k_scatter<<<1024, blk, 0, stream>>>(srcp, dstp, rs, cur, eid, esrc);

    k_lin1<<<(NN + 15) / 16, blk, 0, stream>>>(x, W1l, b1l, W1r, b1r, ws + o_xl1, ws + o_xr1);
    k_gat1<<<12500, blk, 0, stream>>>(rs, eid, esrc, ea, W1e, b1e, att1,
                                      ws + o_xl1, ws + o_xr1, ws + o_h1);
    k_lin2<<<(NN + 15) / 16, blk, 0, stream>>>(ws + o_h1, bias1, W2l, b2l, W2r, b2r,
                                               ws + o_xl2, ws + o_xr2);
    k_gat2<<<12500, blk, 0, stream>>>(rs, eid, esrc, ea, W2e, b2e, att2,
                                      ws + o_xl2, ws + o_xr2, bias2, ws + o_h2);
    k_mlp<<<3125, blk, 0, stream>>>(srcp, dstp, ws + o_h2, ea, Wm1, bm1, Wm2, bm2, out);
}

// Round 5
// 895.552 us; speedup vs baseline: 4.2849x; 1.4839x over previous
//
#include <hip/hip_runtime.h>
#include <math.h>

#define NN 50000
#define EE 600000
#define IND 128
#define HIDD 64
#define NH 4
#define EDD 16
#define OUTD 2
#define C1 256  /* NH*HID */

__device__ __forceinline__ float lrelu(float v){ return v > 0.f ? v : 0.2f*v; }

// ---------------- CSR build: histogram ---------------------------------------
__global__ __launch_bounds__(256) void k_hist(const int* __restrict__ dst, int* __restrict__ cnt)
{
    int stride = gridDim.x * blockDim.x;
    for (int e = blockIdx.x * blockDim.x + threadIdx.x; e < EE; e += stride)
        atomicAdd(&cnt[dst[e]], 1);
}

// ---------------- CSR build: exclusive scan (single block, 1024 thr) ---------
__global__ __launch_bounds__(1024) void k_scan(const int* __restrict__ cnt, int* __restrict__ rs)
{
    __shared__ int wsum[16];
    __shared__ int wpref[16];
    int t = threadIdx.x, lane = t & 63, w = t >> 6;
    int running = 0;
    for (int base = 0; base < NN; base += 1024) {
        int idx = base + t;
        int v = (idx < NN) ? cnt[idx] : 0;
        int sc = v;
#pragma unroll
        for (int off = 1; off < 64; off <<= 1) {
            int u = __shfl_up(sc, off, 64);
            if (lane >= off) sc += u;
        }
        if (lane == 63) wsum[w] = sc;
        __syncthreads();
        if (w == 0 && lane < 16) {
            int x = wsum[lane];
#pragma unroll
            for (int off = 1; off < 16; off <<= 1) {
                int u = __shfl_up(x, off, 64);
                if (lane >= off) x += u;
            }
            wpref[lane] = x;
        }
        __syncthreads();
        int woff = (w == 0) ? 0 : wpref[w - 1];
        if (idx < NN) rs[idx] = running + woff + sc - v;
        running += wpref[15];
        __syncthreads();
    }
    if (t == 0) rs[NN] = running;
}

// ---------------- CSR build: scatter edge ids --------------------------------
__global__ __launch_bounds__(256) void k_scatter(
    const int* __restrict__ src, const int* __restrict__ dst,
    const int* __restrict__ rs, int* __restrict__ cur,
    int* __restrict__ eid, int* __restrict__ esrc)
{
    int stride = gridDim.x * blockDim.x;
    for (int e = blockIdx.x * blockDim.x + threadIdx.x; e < EE; e += stride) {
        int d = dst[e];
        int p = rs[d] + atomicAdd(&cur[d], 1);
        eid[p] = e;
        esrc[p] = src[e];
    }
}

// ---------------- layer 1 node linear: xl1 = x@W1l+b1l, xr1 = x@W1r+b1r ------
__global__ __launch_bounds__(256) void k_lin1(
    const float* __restrict__ x, const float* __restrict__ Wl, const float* __restrict__ bl,
    const float* __restrict__ Wr, const float* __restrict__ br,
    float* __restrict__ xl, float* __restrict__ xr)
{
    __shared__ float As[16 * IND];
    int t = threadIdx.x;
    int row0 = blockIdx.x * 16;
#pragma unroll
    for (int j = 0; j < 8; ++j) {
        int idx = t + j * 256;
        int r = idx >> 7, c = idx & 127;
        As[idx] = (row0 + r < NN) ? x[(size_t)(row0 + r) * IND + c] : 0.f;
    }
    __syncthreads();
    float accl[16], accr[16];
    float bL = bl[t], bR = br[t];
#pragma unroll
    for (int i = 0; i < 16; ++i) { accl[i] = bL; accr[i] = bR; }
    for (int k = 0; k < IND; k += 4) {
        float wl0 = Wl[(k+0) * C1 + t], wl1 = Wl[(k+1) * C1 + t];
        float wl2 = Wl[(k+2) * C1 + t], wl3 = Wl[(k+3) * C1 + t];
        float wr0 = Wr[(k+0) * C1 + t], wr1 = Wr[(k+1) * C1 + t];
        float wr2 = Wr[(k+2) * C1 + t], wr3 = Wr[(k+3) * C1 + t];
#pragma unroll
        for (int i = 0; i < 16; ++i) {
            float4 a = *((const float4*)&As[i * IND + k]);
            accl[i] = fmaf(a.x, wl0, accl[i]); accl[i] = fmaf(a.y, wl1, accl[i]);
            accl[i] = fmaf(a.z, wl2, accl[i]); accl[i] = fmaf(a.w, wl3, accl[i]);
            accr[i] = fmaf(a.x, wr0, accr[i]); accr[i] = fmaf(a.y, wr1, accr[i]);
            accr[i] = fmaf(a.z, wr2, accr[i]); accr[i] = fmaf(a.w, wr3, accr[i]);
        }
    }
#pragma unroll
    for (int i = 0; i < 16; ++i) {
        int r = row0 + i;
        if (r < NN) {
            xl[(size_t)r * C1 + t] = accl[i];
            xr[(size_t)r * C1 + t] = accr[i];
        }
    }
}

// ---------------- layer 1 fused GAT: wave per node, online softmax -----------
__global__ __launch_bounds__(256) void k_gat1(
    const int* __restrict__ rs, const int* __restrict__ eid, const int* __restrict__ esrc,
    const float* __restrict__ ea, const float* __restrict__ We, const float* __restrict__ be,
    const float* __restrict__ att, const float* __restrict__ xl, const float* __restrict__ xr,
    float* __restrict__ h1)
{
    int t = threadIdx.x, lane = t & 63, w = t >> 6;
    int c4 = lane * 4;                 // lane owns 4 contiguous channels, head = lane>>4
    float4 Wreg[16];
#pragma unroll
    for (int k = 0; k < 16; ++k) Wreg[k] = *((const float4*)(We + k * C1 + c4));
    float4 sb4 = *((const float4*)(be + c4));
    float4 sa4 = *((const float4*)(att + c4));
    for (int n = blockIdx.x * 4 + w; n < NN; n += gridDim.x * 4) {
        int beg = rs[n], end = rs[n + 1];
        float4 xr4 = *((const float4*)(xr + (size_t)n * C1 + c4));
        float m = -INFINITY, den = 0.f;
        float4 acc = make_float4(0.f, 0.f, 0.f, 0.f);
        for (int i = beg; i < end; ++i) {
            int e = eid[i], s = esrc[i];
            float4 xl4 = *((const float4*)(xl + (size_t)s * C1 + c4));
            float4 ea0 = *((const float4*)(ea + (size_t)e * EDD));
            float4 ea1 = *((const float4*)(ea + (size_t)e * EDD + 4));
            float4 ea2 = *((const float4*)(ea + (size_t)e * EDD + 8));
            float4 ea3 = *((const float4*)(ea + (size_t)e * EDD + 12));
            float ev[16] = {ea0.x, ea0.y, ea0.z, ea0.w, ea1.x, ea1.y, ea1.z, ea1.w,
                            ea2.x, ea2.y, ea2.z, ea2.w, ea3.x, ea3.y, ea3.z, ea3.w};
            float4 xe = sb4;
#pragma unroll
            for (int k = 0; k < 16; ++k) {
                xe.x = fmaf(ev[k], Wreg[k].x, xe.x);
                xe.y = fmaf(ev[k], Wreg[k].y, xe.y);
                xe.z = fmaf(ev[k], Wreg[k].z, xe.z);
                xe.w = fmaf(ev[k], Wreg[k].w, xe.w);
            }
            float vx = lrelu(xl4.x + xr4.x + xe.x);
            float vy = lrelu(xl4.y + xr4.y + xe.y);
            float vz = lrelu(xl4.z + xr4.z + xe.z);
            float vw = lrelu(xl4.w + xr4.w + xe.w);
            float p = vx * sa4.x + vy * sa4.y + vz * sa4.z + vw * sa4.w;
            // butterfly sum within 16-lane head group -> all lanes get head logit
            p += __shfl_xor(p, 1, 64);
            p += __shfl_xor(p, 2, 64);
            p += __shfl_xor(p, 4, 64);
            p += __shfl_xor(p, 8, 64);
            float mn = fmaxf(m, p);
            float scl = __expf(m - mn);
            float el  = __expf(p - mn);
            den = fmaf(den, scl, el);
            acc.x = fmaf(acc.x, scl, el * xl4.x);
            acc.y = fmaf(acc.y, scl, el * xl4.y);
            acc.z = fmaf(acc.z, scl, el * xl4.z);
            acc.w = fmaf(acc.w, scl, el * xl4.w);
            m = mn;
        }
        float r = den > 0.f ? 1.f / den : 0.f;
        float4 o = make_float4(acc.x * r, acc.y * r, acc.z * r, acc.w * r);
        *((float4*)(h1 + (size_t)n * C1 + c4)) = o;
    }
}

// ---------------- layer 2 node linear (fuses bias1+relu on load) -------------
__global__ __launch_bounds__(256) void k_lin2(
    const float* __restrict__ h1acc, const float* __restrict__ bias1,
    const float* __restrict__ Wl, const float* __restrict__ bl,
    const float* __restrict__ Wr, const float* __restrict__ br,
    float* __restrict__ xl2, float* __restrict__ xr2)
{
    __shared__ float As[16 * 260];
    int t = threadIdx.x;
    int row0 = blockIdx.x * 16;
    float b1 = bias1[t];
#pragma unroll
    for (int j = 0; j < 16; ++j) {
        float v = (row0 + j < NN) ? h1acc[(size_t)(row0 + j) * C1 + t] : 0.f;
        v = v + b1;
        As[j * 260 + t] = v > 0.f ? v : 0.f;
    }
    __syncthreads();
    int col = t & 63, g = t >> 6;
    float accl[4], accr[4];
    float bL = bl[col], bR = br[col];
#pragma unroll
    for (int i = 0; i < 4; ++i) { accl[i] = bL; accr[i] = bR; }
    for (int k = 0; k < C1; k += 4) {
        float wl0 = Wl[(k+0) * HIDD + col], wl1 = Wl[(k+1) * HIDD + col];
        float wl2 = Wl[(k+2) * HIDD + col], wl3 = Wl[(k+3) * HIDD + col];
        float wr0 = Wr[(k+0) * HIDD + col], wr1 = Wr[(k+1) * HIDD + col];
        float wr2 = Wr[(k+2) * HIDD + col], wr3 = Wr[(k+3) * HIDD + col];
#pragma unroll
        for (int i = 0; i < 4; ++i) {
            float4 a = *((const float4*)&As[(g * 4 + i) * 260 + k]);
            accl[i] = fmaf(a.x, wl0, accl[i]); accl[i] = fmaf(a.y, wl1, accl[i]);
            accl[i] = fmaf(a.z, wl2, accl[i]); accl[i] = fmaf(a.w, wl3, accl[i]);
            accr[i] = fmaf(a.x, wr0, accr[i]); accr[i] = fmaf(a.y, wr1, accr[i]);
            accr[i] = fmaf(a.z, wr2, accr[i]); accr[i] = fmaf(a.w, wr3, accr[i]);
        }
    }
#pragma unroll
    for (int i = 0; i < 4; ++i) {
        int r = row0 + g * 4 + i;
        if (r < NN) {
            xl2[(size_t)r * HIDD + col] = accl[i];
            xr2[(size_t)r * HIDD + col] = accr[i];
        }
    }
}

// ---------------- layer 2 fused GAT: wave per node, fuses bias2+relu ---------
__global__ __launch_bounds__(256) void k_gat2(
    const int* __restrict__ rs, const int* __restrict__ eid, const int* __restrict__ esrc,
    const float* __restrict__ ea, const float* __restrict__ We, const float* __restrict__ be,
    const float* __restrict__ att, const float* __restrict__ xl, const float* __restrict__ xr,
    const float* __restrict__ bias2, float* __restrict__ h2)
{
    int t = threadIdx.x, lane = t & 63, w = t >> 6;
    float Wreg[16];
#pragma unroll
    for (int k = 0; k < 16; ++k) Wreg[k] = We[k * HIDD + lane];
    float bev = be[lane], sav = att[lane], b2 = bias2[lane];
    for (int n = blockIdx.x * 4 + w; n < NN; n += gridDim.x * 4) {
        int beg = rs[n], end = rs[n + 1];
        float xrv = xr[(size_t)n * HIDD + lane];
        float m = -INFINITY, den = 0.f, acc = 0.f;
        for (int i = beg; i < end; ++i) {
            int e = eid[i], s = esrc[i];
            float xlv = xl[(size_t)s * HIDD + lane];
            float4 ea0 = *((const float4*)(ea + (size_t)e * EDD));
            float4 ea1 = *((const float4*)(ea + (size_t)e * EDD + 4));
            float4 ea2 = *((const float4*)(ea + (size_t)e * EDD + 8));
            float4 ea3 = *((const float4*)(ea + (size_t)e * EDD + 12));
            float ev[16] = {ea0.x, ea0.y, ea0.z, ea0.w, ea1.x, ea1.y, ea1.z, ea1.w,
                            ea2.x, ea2.y, ea2.z, ea2.w, ea3.x, ea3.y, ea3.z, ea3.w};
            float xe = bev;
#pragma unroll
            for (int k = 0; k < 16; ++k) xe = fmaf(ev[k], Wreg[k], xe);
            float v = lrelu(xlv + xrv + xe);
            float p = v * sav;
            p += __shfl_xor(p, 1, 64);
            p += __shfl_xor(p, 2, 64);
            p += __shfl_xor(p, 4, 64);
            p += __shfl_xor(p, 8, 64);
            p += __shfl_xor(p, 16, 64);
            p += __shfl_xor(p, 32, 64);
            float mn = fmaxf(m, p);
            float scl = __expf(m - mn);
            float el  = __expf(p - mn);
            den = fmaf(den, scl, el);
            acc = fmaf(acc, scl, el * xlv);
            m = mn;
        }
        float r = den > 0.f ? 1.f / den : 0.f;
        float o = fmaf(acc, r, b2);
        h2[(size_t)n * HIDD + lane] = o > 0.f ? o : 0.f;
    }
}

// ---------------- edge-MLP node precompute: P = h2@Wm1[0:64], Q = h2@Wm1[64:128]
// NN = 3125 * 16 exactly -> no bounds checks
__global__ __launch_bounds__(256) void k_pq(
    const float* __restrict__ h2, const float* __restrict__ Wm1,
    float* __restrict__ P, float* __restrict__ Q)
{
    __shared__ float As[16 * 68];      // 16 rows x 64, pitch 68
    int t = threadIdx.x;
    int row0 = blockIdx.x * 16;
    {
        int r = t >> 4, cc = (t & 15) * 4;
        float4 v = *((const float4*)(h2 + (size_t)(row0 + r) * HIDD + cc));
        *((float4*)&As[r * 68 + cc]) = v;
    }
    __syncthreads();
    int col = t & 63, g = t >> 6;      // wave g handles rows g*4..g*4+3
    float accP[4] = {0.f, 0.f, 0.f, 0.f}, accQ[4] = {0.f, 0.f, 0.f, 0.f};
    for (int k = 0; k < 64; k += 4) {
        float wp0 = Wm1[(k+0) * HIDD + col], wp1 = Wm1[(k+1) * HIDD + col];
        float wp2 = Wm1[(k+2) * HIDD + col], wp3 = Wm1[(k+3) * HIDD + col];
        float wq0 = Wm1[(64+k+0) * HIDD + col], wq1 = Wm1[(64+k+1) * HIDD + col];
        float wq2 = Wm1[(64+k+2) * HIDD + col], wq3 = Wm1[(64+k+3) * HIDD + col];
#pragma unroll
        for (int i = 0; i < 4; ++i) {
            float4 a = *((const float4*)&As[(g * 4 + i) * 68 + k]);
            accP[i] = fmaf(a.x, wp0, accP[i]); accP[i] = fmaf(a.y, wp1, accP[i]);
            accP[i] = fmaf(a.z, wp2, accP[i]); accP[i] = fmaf(a.w, wp3, accP[i]);
            accQ[i] = fmaf(a.x, wq0, accQ[i]); accQ[i] = fmaf(a.y, wq1, accQ[i]);
            accQ[i] = fmaf(a.z, wq2, accQ[i]); accQ[i] = fmaf(a.w, wq3, accQ[i]);
        }
    }
#pragma unroll
    for (int i = 0; i < 4; ++i) {
        int r = row0 + g * 4 + i;
        P[(size_t)r * HIDD + col] = accP[i];
        Q[(size_t)r * HIDD + col] = accQ[i];
    }
}

// ---------------- edge MLP: barrier-free streaming, 16 lanes per edge --------
// out[e] = relu(P[src] + Q[dst] + ea@Wm1e + bm1) @ Wm2 + bm2
__global__ __launch_bounds__(256) void k_edge(
    const int* __restrict__ src, const int* __restrict__ dst,
    const float* __restrict__ P, const float* __restrict__ Q,
    const float* __restrict__ ea,
    const float* __restrict__ Wm1, const float* __restrict__ bm1,
    const float* __restrict__ Wm2, const float* __restrict__ bm2,
    float* __restrict__ out)
{
    int t = threadIdx.x, lane = t & 63, w = t >> 6;
    int sub = lane & 15, grp = lane >> 4;
    int c4 = sub * 4;
    float4 Wreg[16];                   // Wm1 rows 128..143, cols c4..c4+3
#pragma unroll
    for (int k = 0; k < 16; ++k) Wreg[k] = *((const float4*)(Wm1 + (size_t)(128 + k) * HIDD + c4));
    float4 b1 = *((const float4*)(bm1 + c4));
    float w200 = Wm2[(c4+0)*2], w201 = Wm2[(c4+0)*2+1];
    float w210 = Wm2[(c4+1)*2], w211 = Wm2[(c4+1)*2+1];
    float w220 = Wm2[(c4+2)*2], w221 = Wm2[(c4+2)*2+1];
    float w230 = Wm2[(c4+3)*2], w231 = Wm2[(c4+3)*2+1];
    float b20 = bm2[0], b21 = bm2[1];
    // EE = 9375 * 16 * 4 exactly; each wave does 4 edges per iteration
    for (int base = blockIdx.x * 16 + w * 4; base < EE; base += gridDim.x * 16) {
        int e = base + grp;
        int s = src[e], d = dst[e];
        float4 pv = *((const float4*)(P + (size_t)s * HIDD + c4));
        float4 qv = *((const float4*)(Q + (size_t)d * HIDD + c4));
        float4 ea0 = *((const float4*)(ea + (size_t)e * EDD));
        float4 ea1 = *((const float4*)(ea + (size_t)e * EDD + 4));
        float4 ea2 = *((const float4*)(ea + (size_t)e * EDD + 8));
        float4 ea3 = *((const float4*)(ea + (size_t)e * EDD + 12));
        float ev[16] = {ea0.x, ea0.y, ea0.z, ea0.w, ea1.x, ea1.y, ea1.z, ea1.w,
                        ea2.x, ea2.y, ea2.z, ea2.w, ea3.x, ea3.y, ea3.z, ea3.w};
        float4 hsum = b1;
#pragma unroll
        for (int k = 0; k < 16; ++k) {
            hsum.x = fmaf(ev[k], Wreg[k].x, hsum.x);
            hsum.y = fmaf(ev[k], Wreg[k].y, hsum.y);
            hsum.z = fmaf(ev[k], Wreg[k].z, hsum.z);
            hsum.w = fmaf(ev[k], Wreg[k].w, hsum.w);
        }
        float hx = fmaxf(hsum.x + pv.x + qv.x, 0.f);
        float hy = fmaxf(hsum.y + pv.y + qv.y, 0.f);
        float hz = fmaxf(hsum.z + pv.z + qv.z, 0.f);
        float hw = fmaxf(hsum.w + pv.w + qv.w, 0.f);
        float p0 = hx * w200 + hy * w210 + hz * w220 + hw * w230;
        float p1 = hx * w201 + hy * w211 + hz * w221 + hw * w231;
        p0 += __shfl_xor(p0, 1, 64);
        p0 += __shfl_xor(p0, 2, 64);
        p0 += __shfl_xor(p0, 4, 64);
        p0 += __shfl_xor(p0, 8, 64);
        p1 += __shfl_xor(p1, 1, 64);
        p1 += __shfl_xor(p1, 2, 64);
        p1 += __shfl_xor(p1, 4, 64);
        p1 += __shfl_xor(p1, 8, 64);
        if (sub == 0) ((float2*)out)[e] = make_float2(p0 + b20, p1 + b21);
    }
}

extern "C" void kernel_launch(void* const* d_in, const int* in_sizes, int n_in,
                              void* d_out, int out_size, void* d_ws, size_t ws_size,
                              hipStream_t stream)
{
    const float* x    = (const float*)d_in[0];
    const int*   ei   = (const int*)d_in[1];
    const float* ea   = (const float*)d_in[2];
    const float* W1l  = (const float*)d_in[3];
    const float* b1l  = (const float*)d_in[4];
    const float* W1r  = (const float*)d_in[5];
    const float* b1r  = (const float*)d_in[6];
    const float* W1e  = (const float*)d_in[7];
    const float* b1e  = (const float*)d_in[8];
    const float* att1 = (const float*)d_in[9];
    const float* bias1= (const float*)d_in[10];
    const float* W2l  = (const float*)d_in[11];
    const float* b2l  = (const float*)d_in[12];
    const float* W2r  = (const float*)d_in[13];
    const float* b2r  = (const float*)d_in[14];
    const float* W2e  = (const float*)d_in[15];
    const float* b2e  = (const float*)d_in[16];
    const float* att2 = (const float*)d_in[17];
    const float* bias2= (const float*)d_in[18];
    const float* Wm1  = (const float*)d_in[19];
    const float* bm1  = (const float*)d_in[20];
    const float* Wm2  = (const float*)d_in[21];
    const float* bm2  = (const float*)d_in[22];
    float* out = (float*)d_out;
    const int* srcp = ei;
    const int* dstp = ei + EE;

    float* ws = (float*)d_ws;
    const size_t NC1 = (size_t)NN * C1;      // 12.8M
    const size_t NH64 = (size_t)NN * HIDD;   // 3.2M
    size_t o_xl1 = 0;
    size_t o_xr1 = o_xl1 + NC1;
    size_t o_h1  = o_xr1 + NC1;
    size_t o_xl2 = o_h1 + NC1;
    size_t o_xr2 = o_xl2 + NH64;
    size_t o_h2  = o_xr2 + NH64;
    size_t o_cnt = o_h2 + NH64;              // int region starts here
    size_t o_rs  = o_cnt + 2 * (size_t)NN;   // cnt + cursor (zeroed together)
    size_t o_eid = o_rs + (size_t)NN + 8;
    size_t o_esrc= o_eid + (size_t)EE;
    // P/Q reuse xl1/xr1 (dead after k_gat1)
    size_t o_P = o_xl1;
    size_t o_Q = o_xl1 + NH64;

    int* cnt  = (int*)(ws + o_cnt);
    int* cur  = cnt + NN;
    int* rs   = (int*)(ws + o_rs);
    int* eid  = (int*)(ws + o_eid);
    int* esrc = (int*)(ws + o_esrc);

    hipMemsetAsync(cnt, 0, 2 * (size_t)NN * sizeof(int), stream);

    dim3 blk(256);
    k_hist<<<1024, blk, 0, stream>>>(dstp, cnt);
    k_scan<<<1, 1024, 0, stream>>>(cnt, rs);
    k_scatter<<<1024, blk, 0, stream>>>(srcp, dstp, rs, cur, eid, esrc);

    k_lin1<<<(NN + 15) / 16, blk, 0, stream>>>(x, W1l, b1l, W1r, b1r, ws + o_xl1, ws + o_xr1);
    k_gat1<<<12500, blk, 0, stream>>>(rs, eid, esrc, ea, W1e, b1e, att1,
                                      ws + o_xl1, ws + o_xr1, ws + o_h1);
    k_lin2<<<(NN + 15) / 16, blk, 0, stream>>>(ws + o_h1, bias1, W2l, b2l, W2r, b2r,
                                               ws + o_xl2, ws + o_xr2);
    k_gat2<<<12500, blk, 0, stream>>>(rs, eid, esrc, ea, W2e, b2e, att2,
                                      ws + o_xl2, ws + o_xr2, bias2, ws + o_h2);
    k_pq<<<3125, blk, 0, stream>>>(ws + o_h2, Wm1, ws + o_P, ws + o_Q);
    k_edge<<<9375, blk, 0, stream>>>(srcp, dstp, ws + o_P, ws + o_Q, ea,
                                     Wm1, bm1, Wm2, bm2, out);
}